// Round 8
// baseline (375.075 us; speedup 1.0000x reference)
//
#include <hip/hip_runtime.h>
#include <hip/hip_bf16.h>

// Problem constants
#define NB 4
#define NT 256
#define NU 100
#define NH 512      // H_ENC = H_DEC = 512
#define NI 512      // INNER
#define NV 1024     // VOCAB
#define MROWS (NB * NT * NU)   // 102400 joint rows

typedef __attribute__((ext_vector_type(4))) float f32x4;
typedef __attribute__((ext_vector_type(8))) __bf16 bf16x8;

// round-to-nearest-even f32 -> bf16 bits
static __device__ __forceinline__ unsigned int f2bf(float f) {
  unsigned int u = __float_as_uint(f);
  return (u + 0x7FFFu + ((u >> 16) & 1u)) >> 16;
}

// tanh(x) = 1 - 2/(1+e^{2x})
static __device__ __forceinline__ float fast_tanh(float x) {
  float e = __expf(2.f * x);
  return 1.f - 2.f * __builtin_amdgcn_rcpf(1.f + e);
}

// async global->LDS, 16B per lane
static __device__ __forceinline__ void gload16(const void* g, void* l) {
  __builtin_amdgcn_global_load_lds(
      (const __attribute__((address_space(1))) unsigned int*)(g),
      (__attribute__((address_space(3))) unsigned int*)(l), 16, 0, 0);
}

// ---------------------------------------------------------------------------
// Merged projections: pe[r][i] = enc[r][:] . W1[i][0:512]   (r < 1024)
//                     pd[r][i] = dec[r][:] . W1[i][512:1024] (r < 400)
// ---------------------------------------------------------------------------
__global__ __launch_bounds__(256) void proj_kernel(
    const float* __restrict__ enc, const float* __restrict__ dec,
    const float* __restrict__ W1, float* __restrict__ pe, float* __restrict__ pd) {
  __shared__ float As[64][17];
  __shared__ float Bs[64][17];
  const int bx = blockIdx.x;
  const float* A;
  float* P;
  int Mrows, colOff, row0;
  if (bx < 16) { A = enc; P = pe; Mrows = NB * NT; colOff = 0;  row0 = bx * 64; }
  else         { A = dec; P = pd; Mrows = NB * NU; colOff = NH; row0 = (bx - 16) * 64; }
  const int col0 = blockIdx.y * 64;
  const int tx = threadIdx.x;
  const int tr = tx >> 4, tc = tx & 15;
  const int lr = tx >> 2, lc = (tx & 3) * 4;
  float acc[4][4] = {};
  for (int k0 = 0; k0 < NH; k0 += 16) {
    float4 av = make_float4(0.f, 0.f, 0.f, 0.f);
    if (row0 + lr < Mrows)
      av = *(const float4*)(A + (size_t)(row0 + lr) * NH + k0 + lc);
    float4 bv = *(const float4*)(W1 + (size_t)(col0 + lr) * (NH + NH) + colOff + k0 + lc);
    As[lr][lc] = av.x; As[lr][lc + 1] = av.y; As[lr][lc + 2] = av.z; As[lr][lc + 3] = av.w;
    Bs[lr][lc] = bv.x; Bs[lr][lc + 1] = bv.y; Bs[lr][lc + 2] = bv.z; Bs[lr][lc + 3] = bv.w;
    __syncthreads();
#pragma unroll
    for (int kk = 0; kk < 16; ++kk) {
      float a4[4], b4[4];
#pragma unroll
      for (int i = 0; i < 4; ++i) { a4[i] = As[tr * 4 + i][kk]; b4[i] = Bs[tc * 4 + i][kk]; }
#pragma unroll
      for (int i = 0; i < 4; ++i)
#pragma unroll
        for (int j = 0; j < 4; ++j) acc[i][j] = fmaf(a4[i], b4[j], acc[i][j]);
    }
    __syncthreads();
  }
#pragma unroll
  for (int i = 0; i < 4; ++i) {
    int r = row0 + tr * 4 + i;
    if (r < Mrows) {
#pragma unroll
      for (int j = 0; j < 4; ++j)
        P[(size_t)r * NI + col0 + tc * 4 + j] = acc[i][j];
    }
  }
}

// ---------------------------------------------------------------------------
// W2 f32 -> bf16, PRE-FRAGGED layout for linear LDS staging/reads:
// w2f chunk g (16B) = [nt 4][kt 8][vb 16][kh 2][lq 4][lr 16] ->
//   v = nt*256 + vb*16 + lr,  k = kt*64 + kh*32 + lq*8  (8 bf16 per chunk)
// ---------------------------------------------------------------------------
__global__ __launch_bounds__(256) void cvt_w2_frag_kernel(
    const float* __restrict__ W2, unsigned short* __restrict__ w2f) {
  int g = blockIdx.x * 256 + threadIdx.x;      // 65536 chunks
  int lr = g & 15, lq = (g >> 4) & 3, kh = (g >> 6) & 1;
  int vb = (g >> 7) & 15, kt = (g >> 11) & 7, nt = (g >> 14) & 3;
  int v = nt * 256 + vb * 16 + lr;
  int k = kt * 64 + kh * 32 + lq * 8;
  const float* src = W2 + (size_t)v * NI + k;
  float4 a = *(const float4*)src;
  float4 b = *(const float4*)(src + 4);
  uint4 o;
  o.x = f2bf(a.x) | (f2bf(a.y) << 16);
  o.y = f2bf(a.z) | (f2bf(a.w) << 16);
  o.z = f2bf(b.x) | (f2bf(b.y) << 16);
  o.w = f2bf(b.z) | (f2bf(b.w) << 16);
  *(uint4*)(w2f + (size_t)g * 8) = o;
}

// ---------------------------------------------------------------------------
// Fused m201-geometry joint GEMM.
// Block: 512 thr / 8 waves (2M x 4N), tile 256 rows x 256 vocab, BK=64.
// Wave tile 128x64 -> ds_read:MFMA = 12:32 = 0.375.
// A tile (256x64 bf16, 32 KB): COMPUTED per K-step = tanh(pe+pd+b1) ->
//   frag-layout ds_write (never touches HBM).
// B tile (256 cols x 64 k, 32 KB): global_load_lds width-16 from pre-fragged
//   w2f -> all LDS traffic is wave-linear, zero bank conflicts, no swizzle.
// One __syncthreads per K-step (8 total); stage(kt+1) issued before
// compute(kt) so its latency hides under 64 MFMAs + tanh VALU.
// Stores ONCE at kernel end (no vmcnt pollution in loop).
// LDS 128 KB -> 1 block/CU, 2 waves/SIMD (VGPR-capped anyway).
// ---------------------------------------------------------------------------
__global__ __launch_bounds__(512, 2) void fused_joint_kernel(
    const float* __restrict__ pe, const float* __restrict__ pd,
    const float* __restrict__ b1, const unsigned short* __restrict__ w2f,
    const float* __restrict__ b2, float* __restrict__ out) {
  __shared__ unsigned char lds[131072];   // [2 buf][A 32K | B 32K]
  const int tx = threadIdx.x;
  const int nt = blockIdx.x & 3, mt = blockIdx.x >> 2;
  const int R0 = mt * 256, C0 = nt * 256;
  const int lane = tx & 63, wid = tx >> 6;
  const int wr = wid >> 2, wc = wid & 3;        // 2M x 4N
  const int lr = lane & 15, lq = lane >> 4;

  // per-thread A-stage slot decode (4 slots, fixed rows/k-offsets across kt)
  int peOff[4], pdOff[4], koff[4], sOff[4];
#pragma unroll
  for (int q = 0; q < 4; ++q) {
    int s = q * 512 + tx;                       // 2048 slots
    int rb = s >> 7, kh = (s >> 6) & 1, lqs = (s >> 4) & 3, lrs = s & 15;
    int rowl = rb * 16 + lrs;                   // 0..255
    int g = R0 + rowl;
    int b = g / (NT * NU);
    int rem = g - b * (NT * NU);
    int t = rem / NU;
    int u = rem - t * NU;
    peOff[q] = (b * NT + t) * NI;
    pdOff[q] = (b * NU + u) * NI;
    koff[q] = kh * 32 + lqs * 8;
    sOff[q] = s * 16;
  }

  // ---- staging helpers ----
#define STAGE_B(KT, BUF) do {                                                 \
    unsigned char* dB_ = lds + (BUF) * 65536 + 32768;                         \
    const unsigned char* src_ =                                               \
        (const unsigned char*)w2f + (((size_t)nt * 8 + (KT)) << 15);          \
    _Pragma("unroll")                                                         \
    for (int q_ = 0; q_ < 4; ++q_) {                                          \
      int c_ = q_ * 512 + tx;                                                 \
      gload16(src_ + c_ * 16, dB_ + c_ * 16);                                 \
    }                                                                         \
  } while (0)

#define STAGE_A(KT, BUF) do {                                                 \
    unsigned char* dA_ = lds + (BUF) * 65536;                                 \
    _Pragma("unroll")                                                         \
    for (int q_ = 0; q_ < 4; ++q_) {                                          \
      int k_ = (KT) * 64 + koff[q_];                                          \
      const float* peP_ = pe + peOff[q_] + k_;                                \
      const float* pdP_ = pd + pdOff[q_] + k_;                                \
      float4 p0 = *(const float4*)peP_, p1 = *(const float4*)(peP_ + 4);      \
      float4 q0 = *(const float4*)pdP_, q1 = *(const float4*)(pdP_ + 4);      \
      float4 c0 = *(const float4*)(b1 + k_), c1 = *(const float4*)(b1 + k_ + 4); \
      uint4 pk;                                                               \
      pk.x = f2bf(fast_tanh(p0.x + q0.x + c0.x)) |                            \
             (f2bf(fast_tanh(p0.y + q0.y + c0.y)) << 16);                     \
      pk.y = f2bf(fast_tanh(p0.z + q0.z + c0.z)) |                            \
             (f2bf(fast_tanh(p0.w + q0.w + c0.w)) << 16);                     \
      pk.z = f2bf(fast_tanh(p1.x + q1.x + c1.x)) |                            \
             (f2bf(fast_tanh(p1.y + q1.y + c1.y)) << 16);                     \
      pk.w = f2bf(fast_tanh(p1.z + q1.z + c1.z)) |                            \
             (f2bf(fast_tanh(p1.w + q1.w + c1.w)) << 16);                     \
      *(uint4*)(dA_ + sOff[q_]) = pk;                                         \
    }                                                                         \
  } while (0)

  f32x4 acc[8][4];
#pragma unroll
  for (int mf = 0; mf < 8; ++mf)
#pragma unroll
    for (int nf = 0; nf < 4; ++nf)
#pragma unroll
      for (int z = 0; z < 4; ++z) acc[mf][nf][z] = 0.f;

  // prologue: stage tile 0
  STAGE_B(0, 0);
  STAGE_A(0, 0);
  __syncthreads();

  for (int kt = 0; kt < 8; ++kt) {
    const int cur = kt & 1;
    if (kt < 7) {                // stage next tile: gloads + tanh, both async
      STAGE_B(kt + 1, cur ^ 1);
      STAGE_A(kt + 1, cur ^ 1);
    }
    const unsigned char* Ab = lds + cur * 65536;
    const unsigned char* Bb = Ab + 32768;
#pragma unroll
    for (int kh = 0; kh < 2; ++kh) {
      bf16x8 bfv[4], af4[4];
#pragma unroll
      for (int nf = 0; nf < 4; ++nf)
        bfv[nf] = *(const bf16x8*)(Bb + (wc * 4 + nf) * 2048 + kh * 1024 + lane * 16);
#pragma unroll
      for (int m = 0; m < 4; ++m)
        af4[m] = *(const bf16x8*)(Ab + (wr * 8 + m) * 2048 + kh * 1024 + lane * 16);
      __builtin_amdgcn_s_setprio(1);
#pragma unroll
      for (int m = 0; m < 4; ++m)
#pragma unroll
        for (int nf = 0; nf < 4; ++nf)
          acc[m][nf] = __builtin_amdgcn_mfma_f32_16x16x32_bf16(
              af4[m], bfv[nf], acc[m][nf], 0, 0, 0);
      __builtin_amdgcn_s_setprio(0);
#pragma unroll
      for (int m = 0; m < 4; ++m)
        af4[m] = *(const bf16x8*)(Ab + (wr * 8 + 4 + m) * 2048 + kh * 1024 + lane * 16);
      __builtin_amdgcn_s_setprio(1);
#pragma unroll
      for (int m = 0; m < 4; ++m)
#pragma unroll
        for (int nf = 0; nf < 4; ++nf)
          acc[4 + m][nf] = __builtin_amdgcn_mfma_f32_16x16x32_bf16(
              af4[m], bfv[nf], acc[4 + m][nf], 0, 0, 0);
      __builtin_amdgcn_s_setprio(0);
    }
    __syncthreads();             // drains stage(kt+1) gloads + A ds_writes
  }
#undef STAGE_A
#undef STAGE_B

  // epilogue: + b2, fp32 stores (64B per quarter-wave, once per kernel)
#pragma unroll
  for (int nf = 0; nf < 4; ++nf) {
    int col = C0 + wc * 64 + nf * 16 + lr;
    float bb = b2[col];
#pragma unroll
    for (int mf = 0; mf < 8; ++mf) {
#pragma unroll
      for (int j = 0; j < 4; ++j) {
        int grow = R0 + wr * 128 + mf * 16 + lq * 4 + j;
        out[(size_t)grow * NV + col] = acc[mf][nf][j] + bb;
      }
    }
  }
}

extern "C" void kernel_launch(void* const* d_in, const int* in_sizes, int n_in,
                              void* d_out, int out_size, void* d_ws, size_t ws_size,
                              hipStream_t stream) {
  const float* enc = (const float*)d_in[0];
  const float* dec = (const float*)d_in[1];
  const float* W1  = (const float*)d_in[2];
  const float* b1  = (const float*)d_in[3];
  const float* W2  = (const float*)d_in[4];
  const float* b2  = (const float*)d_in[5];
  float* out = (float*)d_out;
  char* ws = (char*)d_ws;

  float* pe = (float*)ws;                                   // 2 MB
  float* pd = (float*)(ws + (2u << 20));                    // 0.8 MB
  unsigned short* w2f = (unsigned short*)(ws + (3u << 20)); // 1 MB, fragged

  proj_kernel<<<dim3(23, 8), 256, 0, stream>>>(enc, dec, W1, pe, pd);
  cvt_w2_frag_kernel<<<256, 256, 0, stream>>>(W2, w2f);
  fused_joint_kernel<<<(MROWS / 256) * (NV / 256), 512, 0, stream>>>(
      pe, pd, b1, w2f, b2, out);
}

// Round 9
// 311.109 us; speedup vs baseline: 1.2056x; 1.2056x over previous
//
#include <hip/hip_runtime.h>
#include <hip/hip_bf16.h>

// Problem constants
#define NB 4
#define NT 256
#define NU 100
#define NH 512      // H_ENC = H_DEC = 512
#define NI 512      // INNER
#define NV 1024     // VOCAB
#define MROWS (NB * NT * NU)   // 102400 joint rows

typedef __attribute__((ext_vector_type(4))) float f32x4;
typedef __attribute__((ext_vector_type(8))) __bf16 bf16x8;

// round-to-nearest-even f32 -> bf16 bits
static __device__ __forceinline__ unsigned int f2bf(float f) {
  unsigned int u = __float_as_uint(f);
  return (u + 0x7FFFu + ((u >> 16) & 1u)) >> 16;
}

// tanh(x) = 1 - 2/(1+e^{2x})
static __device__ __forceinline__ float fast_tanh(float x) {
  float e = __expf(2.f * x);
  return 1.f - 2.f * __builtin_amdgcn_rcpf(1.f + e);
}

// async global->LDS, 16B per lane
static __device__ __forceinline__ void gload16(const void* g, void* l) {
  __builtin_amdgcn_global_load_lds(
      (const __attribute__((address_space(1))) unsigned int*)(g),
      (__attribute__((address_space(3))) unsigned int*)(l), 16, 0, 0);
}

// ---------------------------------------------------------------------------
// Merged projections: pe[r][i] = enc[r][:] . W1[i][0:512]   (r < 1024)
//                     pd[r][i] = dec[r][:] . W1[i][512:1024] (r < 400)
// ---------------------------------------------------------------------------
__global__ __launch_bounds__(256) void proj_kernel(
    const float* __restrict__ enc, const float* __restrict__ dec,
    const float* __restrict__ W1, float* __restrict__ pe, float* __restrict__ pd) {
  __shared__ float As[64][17];
  __shared__ float Bs[64][17];
  const int bx = blockIdx.x;
  const float* A;
  float* P;
  int Mrows, colOff, row0;
  if (bx < 16) { A = enc; P = pe; Mrows = NB * NT; colOff = 0;  row0 = bx * 64; }
  else         { A = dec; P = pd; Mrows = NB * NU; colOff = NH; row0 = (bx - 16) * 64; }
  const int col0 = blockIdx.y * 64;
  const int tx = threadIdx.x;
  const int tr = tx >> 4, tc = tx & 15;
  const int lr = tx >> 2, lc = (tx & 3) * 4;
  float acc[4][4] = {};
  for (int k0 = 0; k0 < NH; k0 += 16) {
    float4 av = make_float4(0.f, 0.f, 0.f, 0.f);
    if (row0 + lr < Mrows)
      av = *(const float4*)(A + (size_t)(row0 + lr) * NH + k0 + lc);
    float4 bv = *(const float4*)(W1 + (size_t)(col0 + lr) * (NH + NH) + colOff + k0 + lc);
    As[lr][lc] = av.x; As[lr][lc + 1] = av.y; As[lr][lc + 2] = av.z; As[lr][lc + 3] = av.w;
    Bs[lr][lc] = bv.x; Bs[lr][lc + 1] = bv.y; Bs[lr][lc + 2] = bv.z; Bs[lr][lc + 3] = bv.w;
    __syncthreads();
#pragma unroll
    for (int kk = 0; kk < 16; ++kk) {
      float a4[4], b4[4];
#pragma unroll
      for (int i = 0; i < 4; ++i) { a4[i] = As[tr * 4 + i][kk]; b4[i] = Bs[tc * 4 + i][kk]; }
#pragma unroll
      for (int i = 0; i < 4; ++i)
#pragma unroll
        for (int j = 0; j < 4; ++j) acc[i][j] = fmaf(a4[i], b4[j], acc[i][j]);
    }
    __syncthreads();
  }
#pragma unroll
  for (int i = 0; i < 4; ++i) {
    int r = row0 + tr * 4 + i;
    if (r < Mrows) {
#pragma unroll
      for (int j = 0; j < 4; ++j)
        P[(size_t)r * NI + col0 + tc * 4 + j] = acc[i][j];
    }
  }
}

// ---------------------------------------------------------------------------
// W2 f32 -> bf16, PRE-FRAGGED layout for linear LDS staging/reads:
// w2f chunk g (16B) = [nt 4][kt 8][vb 16][kh 2][lq 4][lr 16] ->
//   v = nt*256 + vb*16 + lr,  k = kt*64 + kh*32 + lq*8  (8 bf16 per chunk)
// ---------------------------------------------------------------------------
__global__ __launch_bounds__(256) void cvt_w2_frag_kernel(
    const float* __restrict__ W2, unsigned short* __restrict__ w2f) {
  int g = blockIdx.x * 256 + threadIdx.x;      // 65536 chunks
  int lr = g & 15, lq = (g >> 4) & 3, kh = (g >> 6) & 1;
  int vb = (g >> 7) & 15, kt = (g >> 11) & 7, nt = (g >> 14) & 3;
  int v = nt * 256 + vb * 16 + lr;
  int k = kt * 64 + kh * 32 + lq * 8;
  const float* src = W2 + (size_t)v * NI + k;
  float4 a = *(const float4*)src;
  float4 b = *(const float4*)(src + 4);
  uint4 o;
  o.x = f2bf(a.x) | (f2bf(a.y) << 16);
  o.y = f2bf(a.z) | (f2bf(a.w) << 16);
  o.z = f2bf(b.x) | (f2bf(b.y) << 16);
  o.w = f2bf(b.z) | (f2bf(b.w) << 16);
  *(uint4*)(w2f + (size_t)g * 8) = o;
}

// ---------------------------------------------------------------------------
// Fused m201-geometry joint GEMM, COALESCED computed-A staging.
// Block: 512 thr / 8 waves (2M x 4N), tile 256 rows x 256 vocab, BK=64.
// Wave tile 128x64 -> ds_read:MFMA = 12:32 = 0.375.
// A tile (256x64 bf16, 32 KB): computed per K-step = tanh(pe+pd+b1).
//   Slot map: s = q*512+tx -> row = s>>3, c = s&7 (k-chunk). 8 lanes sweep
//   one row's 256B contiguously (coalesced); LDS chunk = rb*128 + lr*8 +
//   (c ^ (lr&7)) -> ds_write bank-uniform, ds_read_b128 2-way (free).
// B tile: global_load_lds width-16 from pre-fragged w2f (linear, 0-conflict).
// One __syncthreads per K-step; stage(kt+1) (gloads + tanh + ds_write, all
// to buf^1) issued before compute(kt) so latency hides under 64 MFMAs.
// Stores ONCE at kernel end.
// ---------------------------------------------------------------------------
__global__ __launch_bounds__(512, 2) void fused_joint_kernel(
    const float* __restrict__ pe, const float* __restrict__ pd,
    const float* __restrict__ b1, const unsigned short* __restrict__ w2f,
    const float* __restrict__ b2, float* __restrict__ out) {
  __shared__ unsigned char lds[131072];   // [2 buf][A 32K | B 32K]
  const int tx = threadIdx.x;
  const int nt = blockIdx.x & 3, mt = blockIdx.x >> 2;
  const int R0 = mt * 256, C0 = nt * 256;
  const int lane = tx & 63, wid = tx >> 6;
  const int wr = wid >> 2, wc = wid & 3;        // 2M x 4N
  const int lr = lane & 15, lq = lane >> 4;

  // A-stage precompute: 4 slots/thread, s = q*512 + tx.
  // row = s>>3 = q*64 + (tx>>3)  (c = s&7 = tx&7, invariant in q)
  const int kc = (tx & 7) * 8;                  // k offset within BK tile
  int peOff[4], pdOff[4], aOff[4];
#pragma unroll
  for (int q = 0; q < 4; ++q) {
    int rowl = q * 64 + (tx >> 3);              // 0..255
    int g = R0 + rowl;
    int b = g / (NT * NU);
    int rem = g - b * (NT * NU);
    int t = rem / NU;
    int u = rem - t * NU;
    peOff[q] = (b * NT + t) * NI;
    pdOff[q] = (b * NU + u) * NI;
    int rb = rowl >> 4, lrr = rowl & 15;
    aOff[q] = (rb * 128 + lrr * 8 + ((tx & 7) ^ (lrr & 7))) * 16;
  }
  // af read swizzle per kh (lane-constant)
  const int afSw0 = ((0 * 4 + lq) ^ (lr & 7)) << 4;
  const int afSw1 = ((1 * 4 + lq) ^ (lr & 7)) << 4;

#define STAGE_B(KT, BUF) do {                                                 \
    unsigned char* dB_ = lds + (BUF) * 65536 + 32768;                         \
    const unsigned char* src_ =                                               \
        (const unsigned char*)w2f + (((size_t)nt * 8 + (KT)) << 15);          \
    _Pragma("unroll")                                                         \
    for (int q_ = 0; q_ < 4; ++q_) {                                          \
      int c_ = q_ * 512 + tx;                                                 \
      gload16(src_ + c_ * 16, dB_ + c_ * 16);                                 \
    }                                                                         \
  } while (0)

#define STAGE_A(KT, BUF) do {                                                 \
    unsigned char* dA_ = lds + (BUF) * 65536;                                 \
    const int k_ = (KT) * 64 + kc;                                            \
    float4 c0 = *(const float4*)(b1 + k_);                                    \
    float4 c1 = *(const float4*)(b1 + k_ + 4);                                \
    _Pragma("unroll")                                                         \
    for (int q_ = 0; q_ < 4; ++q_) {                                          \
      const float* peP_ = pe + peOff[q_] + k_;                                \
      const float* pdP_ = pd + pdOff[q_] + k_;                                \
      float4 p0 = *(const float4*)peP_, p1 = *(const float4*)(peP_ + 4);      \
      float4 q0 = *(const float4*)pdP_, q1 = *(const float4*)(pdP_ + 4);      \
      uint4 pk;                                                               \
      pk.x = f2bf(fast_tanh(p0.x + q0.x + c0.x)) |                            \
             (f2bf(fast_tanh(p0.y + q0.y + c0.y)) << 16);                     \
      pk.y = f2bf(fast_tanh(p0.z + q0.z + c0.z)) |                            \
             (f2bf(fast_tanh(p0.w + q0.w + c0.w)) << 16);                     \
      pk.z = f2bf(fast_tanh(p1.x + q1.x + c1.x)) |                            \
             (f2bf(fast_tanh(p1.y + q1.y + c1.y)) << 16);                     \
      pk.w = f2bf(fast_tanh(p1.z + q1.z + c1.z)) |                            \
             (f2bf(fast_tanh(p1.w + q1.w + c1.w)) << 16);                     \
      *(uint4*)(dA_ + aOff[q_]) = pk;                                         \
    }                                                                         \
  } while (0)

  f32x4 acc[8][4];
#pragma unroll
  for (int mf = 0; mf < 8; ++mf)
#pragma unroll
    for (int nf = 0; nf < 4; ++nf)
#pragma unroll
      for (int z = 0; z < 4; ++z) acc[mf][nf][z] = 0.f;

  // prologue: stage tile 0
  STAGE_B(0, 0);
  STAGE_A(0, 0);
  __syncthreads();

  for (int kt = 0; kt < 8; ++kt) {
    const int cur = kt & 1;
    if (kt < 7) {                 // next tile: B gloads async, A tanh on VALU
      STAGE_B(kt + 1, cur ^ 1);
      STAGE_A(kt + 1, cur ^ 1);
    }
    const unsigned char* Ab = lds + cur * 65536;
    const unsigned char* Bb = Ab + 32768;
#pragma unroll
    for (int kh = 0; kh < 2; ++kh) {
      const int sw = kh ? afSw1 : afSw0;
      bf16x8 bfv[4], af4[4];
#pragma unroll
      for (int nf = 0; nf < 4; ++nf)
        bfv[nf] = *(const bf16x8*)(Bb + (wc * 4 + nf) * 2048 + kh * 1024 + lane * 16);
#pragma unroll
      for (int m = 0; m < 4; ++m)
        af4[m] = *(const bf16x8*)(Ab + (wr * 8 + m) * 2048 + lr * 128 + sw);
      __builtin_amdgcn_s_setprio(1);
#pragma unroll
      for (int m = 0; m < 4; ++m)
#pragma unroll
        for (int nf = 0; nf < 4; ++nf)
          acc[m][nf] = __builtin_amdgcn_mfma_f32_16x16x32_bf16(
              af4[m], bfv[nf], acc[m][nf], 0, 0, 0);
      __builtin_amdgcn_s_setprio(0);
#pragma unroll
      for (int m = 0; m < 4; ++m)
        af4[m] = *(const bf16x8*)(Ab + (wr * 8 + 4 + m) * 2048 + lr * 128 + sw);
      __builtin_amdgcn_s_setprio(1);
#pragma unroll
      for (int m = 0; m < 4; ++m)
#pragma unroll
        for (int nf = 0; nf < 4; ++nf)
          acc[4 + m][nf] = __builtin_amdgcn_mfma_f32_16x16x32_bf16(
              af4[m], bfv[nf], acc[4 + m][nf], 0, 0, 0);
      __builtin_amdgcn_s_setprio(0);
    }
    __syncthreads();              // drains stage(kt+1) gloads + A ds_writes
  }
#undef STAGE_A
#undef STAGE_B

  // epilogue: + b2, fp32 stores (64B per quarter-wave, once per kernel)
#pragma unroll
  for (int nf = 0; nf < 4; ++nf) {
    int col = C0 + wc * 64 + nf * 16 + lr;
    float bb = b2[col];
#pragma unroll
    for (int mf = 0; mf < 8; ++mf) {
#pragma unroll
      for (int j = 0; j < 4; ++j) {
        int grow = R0 + wr * 128 + mf * 16 + lq * 4 + j;
        out[(size_t)grow * NV + col] = acc[mf][nf][j] + bb;
      }
    }
  }
}

extern "C" void kernel_launch(void* const* d_in, const int* in_sizes, int n_in,
                              void* d_out, int out_size, void* d_ws, size_t ws_size,
                              hipStream_t stream) {
  const float* enc = (const float*)d_in[0];
  const float* dec = (const float*)d_in[1];
  const float* W1  = (const float*)d_in[2];
  const float* b1  = (const float*)d_in[3];
  const float* W2  = (const float*)d_in[4];
  const float* b2  = (const float*)d_in[5];
  float* out = (float*)d_out;
  char* ws = (char*)d_ws;

  float* pe = (float*)ws;                                   // 2 MB
  float* pd = (float*)(ws + (2u << 20));                    // 0.8 MB
  unsigned short* w2f = (unsigned short*)(ws + (3u << 20)); // 1 MB, fragged

  proj_kernel<<<dim3(23, 8), 256, 0, stream>>>(enc, dec, W1, pe, pd);
  cvt_w2_frag_kernel<<<256, 256, 0, stream>>>(W2, w2f);
  fused_joint_kernel<<<(MROWS / 256) * (NV / 256), 512, 0, stream>>>(
      pe, pd, b1, w2f, b2, out);
}

// Round 10
// 236.636 us; speedup vs baseline: 1.5850x; 1.3147x over previous
//
#include <hip/hip_runtime.h>
#include <hip/hip_bf16.h>

// Problem constants
#define NB 4
#define NT 256
#define NU 100
#define NH 512      // H_ENC = H_DEC = 512
#define NI 512      // INNER
#define NV 1024     // VOCAB
#define MROWS (NB * NT * NU)   // 102400 joint rows

typedef __attribute__((ext_vector_type(4))) float f32x4;
typedef __attribute__((ext_vector_type(8))) __bf16 bf16x8;

// round-to-nearest-even f32 -> bf16 bits
static __device__ __forceinline__ unsigned int f2bf(float f) {
  unsigned int u = __float_as_uint(f);
  return (u + 0x7FFFu + ((u >> 16) & 1u)) >> 16;
}

// tanh(x) = 1 - 2/(1+e^{2x})
static __device__ __forceinline__ float fast_tanh(float x) {
  float e = __expf(2.f * x);
  return 1.f - 2.f * __builtin_amdgcn_rcpf(1.f + e);
}

// packed RNE f32x2 -> bf16x2 (single instruction)
static __device__ __forceinline__ unsigned int cvt_pk_bf16(float lo, float hi) {
  unsigned int r;
  asm("v_cvt_pk_bf16_f32 %0, %1, %2" : "=v"(r) : "v"(lo), "v"(hi));
  return r;
}

// async global->LDS, 16B per lane
static __device__ __forceinline__ void gload16(const void* g, void* l) {
  __builtin_amdgcn_global_load_lds(
      (const __attribute__((address_space(1))) unsigned int*)(g),
      (__attribute__((address_space(3))) unsigned int*)(l), 16, 0, 0);
}

// ---------------------------------------------------------------------------
// Merged projections: pe[r][i] = enc[r][:] . W1[i][0:512]   (r < 1024)
//                     pd[r][i] = dec[r][:] . W1[i][512:1024] (r < 400)
// ---------------------------------------------------------------------------
__global__ __launch_bounds__(256) void proj_kernel(
    const float* __restrict__ enc, const float* __restrict__ dec,
    const float* __restrict__ W1, float* __restrict__ pe, float* __restrict__ pd) {
  __shared__ float As[64][17];
  __shared__ float Bs[64][17];
  const int bx = blockIdx.x;
  const float* A;
  float* P;
  int Mrows, colOff, row0;
  if (bx < 16) { A = enc; P = pe; Mrows = NB * NT; colOff = 0;  row0 = bx * 64; }
  else         { A = dec; P = pd; Mrows = NB * NU; colOff = NH; row0 = (bx - 16) * 64; }
  const int col0 = blockIdx.y * 64;
  const int tx = threadIdx.x;
  const int tr = tx >> 4, tc = tx & 15;
  const int lr = tx >> 2, lc = (tx & 3) * 4;
  float acc[4][4] = {};
  for (int k0 = 0; k0 < NH; k0 += 16) {
    float4 av = make_float4(0.f, 0.f, 0.f, 0.f);
    if (row0 + lr < Mrows)
      av = *(const float4*)(A + (size_t)(row0 + lr) * NH + k0 + lc);
    float4 bv = *(const float4*)(W1 + (size_t)(col0 + lr) * (NH + NH) + colOff + k0 + lc);
    As[lr][lc] = av.x; As[lr][lc + 1] = av.y; As[lr][lc + 2] = av.z; As[lr][lc + 3] = av.w;
    Bs[lr][lc] = bv.x; Bs[lr][lc + 1] = bv.y; Bs[lr][lc + 2] = bv.z; Bs[lr][lc + 3] = bv.w;
    __syncthreads();
#pragma unroll
    for (int kk = 0; kk < 16; ++kk) {
      float a4[4], b4[4];
#pragma unroll
      for (int i = 0; i < 4; ++i) { a4[i] = As[tr * 4 + i][kk]; b4[i] = Bs[tc * 4 + i][kk]; }
#pragma unroll
      for (int i = 0; i < 4; ++i)
#pragma unroll
        for (int j = 0; j < 4; ++j) acc[i][j] = fmaf(a4[i], b4[j], acc[i][j]);
    }
    __syncthreads();
  }
#pragma unroll
  for (int i = 0; i < 4; ++i) {
    int r = row0 + tr * 4 + i;
    if (r < Mrows) {
#pragma unroll
      for (int j = 0; j < 4; ++j)
        P[(size_t)r * NI + col0 + tc * 4 + j] = acc[i][j];
    }
  }
}

// ---------------------------------------------------------------------------
// W2 f32 -> bf16, PRE-FRAGGED for BK=32 linear staging/reads:
// chunk g (16B) = [nt 4][kt 16][cb 16][lq 4][lr 16] ->
//   v = nt*256 + cb*16 + lr,  k = kt*32 + lq*8
// ---------------------------------------------------------------------------
__global__ __launch_bounds__(256) void cvt_w2_frag_kernel(
    const float* __restrict__ W2, unsigned short* __restrict__ w2f) {
  int g = blockIdx.x * 256 + threadIdx.x;      // 65536 chunks
  int lr = g & 15, lq = (g >> 4) & 3;
  int cb = (g >> 6) & 15, kt = (g >> 10) & 15, nt = (g >> 14) & 3;
  int v = nt * 256 + cb * 16 + lr;
  int k = kt * 32 + lq * 8;
  const float* src = W2 + (size_t)v * NI + k;
  float4 a = *(const float4*)src;
  float4 b = *(const float4*)(src + 4);
  uint4 o;
  o.x = f2bf(a.x) | (f2bf(a.y) << 16);
  o.y = f2bf(a.z) | (f2bf(a.w) << 16);
  o.z = f2bf(b.x) | (f2bf(b.y) << 16);
  o.w = f2bf(b.z) | (f2bf(b.w) << 16);
  *(uint4*)(w2f + (size_t)g * 8) = o;
}

// ---------------------------------------------------------------------------
// Fused joint GEMM, 2-blocks/CU geometry.
// Block: 512 thr / 8 waves (2M x 4N), tile 128 rows x 256 vocab, BK=32,
// 16 K-steps. Wave tile 64x64, acc[4][4] = 64 regs; launch_bounds(512,4)
// forces <=128 VGPR -> 16 waves/CU (4/SIMD) with LDS 48 KB dbuf.
// A tile (128x32 bf16, 8 KB): computed = tanh(pe+pd+b1); ds_write linear
//   (phys chunk = tx), read swizzle phys_slot = lq ^ ((row>>1)&3) -> 8
//   bank-groups, 2-way (free). cvt_pk_bf16 packs pairs in 1 inst.
// B tile (256x32, 16 KB): global_load_lds width-16 from pre-fragged w2f.
// Schedule/step: B-gloads(kt+1) -> pe/pd reg loads(kt+1) -> frag ds_reads(kt)
//   -> MFMA(kt) -> tanh+ds_write(kt+1) -> barrier.  Stores once at end.
// ---------------------------------------------------------------------------
__global__ __launch_bounds__(512, 4) void fused_joint_kernel(
    const float* __restrict__ pe, const float* __restrict__ pd,
    const float* __restrict__ b1, const unsigned short* __restrict__ w2f,
    const float* __restrict__ b2, float* __restrict__ out) {
  __shared__ unsigned char lds[49152];   // [2 buf][A 8K | B 16K]
  const int tx = threadIdx.x;
  const int nt = blockIdx.x & 3, mt = blockIdx.x >> 2;
  const int R0 = mt * 128, C0 = nt * 256;
  const int lane = tx & 63, wid = tx >> 6;
  const int wr = wid >> 2, wc = wid & 3;        // 2M x 4N
  const int lr = lane & 15, lq = lane >> 4;

  // A-stage decode (1 chunk/thread): row = tx>>2, phys slot = tx&3,
  // logical k-slot = phys ^ ((row>>1)&3)
  const int arow = tx >> 2;
  const int kc = ((tx & 3) ^ ((tx >> 3) & 3)) * 8;   // k offset in BK tile
  int peOff, pdOff;
  {
    int g = R0 + arow;
    int b = g / (NT * NU);
    int rem = g - b * (NT * NU);
    int t = rem / NU;
    int u = rem - t * NU;
    peOff = (b * NT + t) * NI;
    pdOff = (b * NU + u) * NI;
  }
  // af read swizzle (lane-constant): phys slot for logical lq
  const int afSw = ((lq ^ ((lr >> 1) & 3)) << 4);

#define STAGE_B(KT, BUF) do {                                                 \
    unsigned char* dB_ = lds + (BUF) * 24576 + 8192;                          \
    const unsigned char* src_ =                                               \
        (const unsigned char*)w2f + (((size_t)nt * 16 + (KT)) << 14);         \
    gload16(src_ + tx * 16, dB_ + tx * 16);                                   \
    gload16(src_ + (512 + tx) * 16, dB_ + (512 + tx) * 16);                   \
  } while (0)

  f32x4 acc[4][4];
#pragma unroll
  for (int mf = 0; mf < 4; ++mf)
#pragma unroll
    for (int nf = 0; nf < 4; ++nf)
#pragma unroll
      for (int z = 0; z < 4; ++z) acc[mf][nf][z] = 0.f;

  // prologue: stage tile 0
  STAGE_B(0, 0);
  {
    const int k_ = kc;
    float4 p0 = *(const float4*)(pe + peOff + k_);
    float4 p1 = *(const float4*)(pe + peOff + k_ + 4);
    float4 q0 = *(const float4*)(pd + pdOff + k_);
    float4 q1 = *(const float4*)(pd + pdOff + k_ + 4);
    float4 c0 = *(const float4*)(b1 + k_);
    float4 c1 = *(const float4*)(b1 + k_ + 4);
    uint4 pk;
    pk.x = cvt_pk_bf16(fast_tanh(p0.x + q0.x + c0.x), fast_tanh(p0.y + q0.y + c0.y));
    pk.y = cvt_pk_bf16(fast_tanh(p0.z + q0.z + c0.z), fast_tanh(p0.w + q0.w + c0.w));
    pk.z = cvt_pk_bf16(fast_tanh(p1.x + q1.x + c1.x), fast_tanh(p1.y + q1.y + c1.y));
    pk.w = cvt_pk_bf16(fast_tanh(p1.z + q1.z + c1.z), fast_tanh(p1.w + q1.w + c1.w));
    *(uint4*)(lds + tx * 16) = pk;
  }
  __syncthreads();

  for (int kt = 0; kt < 16; ++kt) {
    const int cur = kt & 1;
    unsigned char* nbuf = lds + (cur ^ 1) * 24576;
    const unsigned char* Ab = lds + cur * 24576;
    const unsigned char* Bb = Ab + 8192;

    if (kt < 15) STAGE_B(kt + 1, cur ^ 1);

    // issue next A-tile's global loads early (latency under MFMA)
    float4 p0, p1, q0, q1, c0, c1;
    if (kt < 15) {
      const int k_ = (kt + 1) * 32 + kc;
      p0 = *(const float4*)(pe + peOff + k_);
      p1 = *(const float4*)(pe + peOff + k_ + 4);
      q0 = *(const float4*)(pd + pdOff + k_);
      q1 = *(const float4*)(pd + pdOff + k_ + 4);
      c0 = *(const float4*)(b1 + k_);
      c1 = *(const float4*)(b1 + k_ + 4);
    }

    // fragment reads for kt
    bf16x8 af4[4];
#pragma unroll
    for (int mf = 0; mf < 4; ++mf)
      af4[mf] = *(const bf16x8*)(Ab + (wr * 64 + mf * 16 + lr) * 64 + afSw);

    __builtin_amdgcn_s_setprio(1);
#pragma unroll
    for (int nf = 0; nf < 4; ++nf) {
      bf16x8 bfv = *(const bf16x8*)(Bb + ((wc * 4 + nf) * 64 + lq * 16 + lr) * 16);
#pragma unroll
      for (int mf = 0; mf < 4; ++mf)
        acc[mf][nf] = __builtin_amdgcn_mfma_f32_16x16x32_bf16(
            af4[mf], bfv, acc[mf][nf], 0, 0, 0);
    }
    __builtin_amdgcn_s_setprio(0);

    // finish next A tile: tanh + linear ds_write (write-late)
    if (kt < 15) {
      uint4 pk;
      pk.x = cvt_pk_bf16(fast_tanh(p0.x + q0.x + c0.x), fast_tanh(p0.y + q0.y + c0.y));
      pk.y = cvt_pk_bf16(fast_tanh(p0.z + q0.z + c0.z), fast_tanh(p0.w + q0.w + c0.w));
      pk.z = cvt_pk_bf16(fast_tanh(p1.x + q1.x + c1.x), fast_tanh(p1.y + q1.y + c1.y));
      pk.w = cvt_pk_bf16(fast_tanh(p1.z + q1.z + c1.z), fast_tanh(p1.w + q1.w + c1.w));
      *(uint4*)(nbuf + tx * 16) = pk;
      __syncthreads();           // drains B gloads + A ds_writes
    }
  }
#undef STAGE_B

  // epilogue: + b2, fp32 stores (64B per 16-lane group, once per kernel)
#pragma unroll
  for (int nf = 0; nf < 4; ++nf) {
    int col = C0 + wc * 64 + nf * 16 + lr;
    float bb = b2[col];
#pragma unroll
    for (int mf = 0; mf < 4; ++mf) {
#pragma unroll
      for (int j = 0; j < 4; ++j) {
        int grow = R0 + wr * 64 + mf * 16 + lq * 4 + j;
        out[(size_t)grow * NV + col] = acc[mf][nf][j] + bb;
      }
    }
  }
}

extern "C" void kernel_launch(void* const* d_in, const int* in_sizes, int n_in,
                              void* d_out, int out_size, void* d_ws, size_t ws_size,
                              hipStream_t stream) {
  const float* enc = (const float*)d_in[0];
  const float* dec = (const float*)d_in[1];
  const float* W1  = (const float*)d_in[2];
  const float* b1  = (const float*)d_in[3];
  const float* W2  = (const float*)d_in[4];
  const float* b2  = (const float*)d_in[5];
  float* out = (float*)d_out;
  char* ws = (char*)d_ws;

  float* pe = (float*)ws;                                   // 2 MB
  float* pd = (float*)(ws + (2u << 20));                    // 0.8 MB
  unsigned short* w2f = (unsigned short*)(ws + (3u << 20)); // 1 MB, fragged

  proj_kernel<<<dim3(23, 8), 256, 0, stream>>>(enc, dec, W1, pe, pd);
  cvt_w2_frag_kernel<<<256, 256, 0, stream>>>(W2, w2f);
  fused_joint_kernel<<<(MROWS / 128) * (NV / 256), 512, 0, stream>>>(
      pe, pd, b1, w2f, b2, out);
}

// Round 11
// 228.622 us; speedup vs baseline: 1.6406x; 1.0351x over previous
//
#include <hip/hip_runtime.h>
#include <hip/hip_bf16.h>

// Problem constants
#define NB 4
#define NT 256
#define NU 100
#define NH 512      // H_ENC = H_DEC = 512
#define NI 512      // INNER
#define NV 1024     // VOCAB
#define MROWS (NB * NT * NU)   // 102400 joint rows

typedef __attribute__((ext_vector_type(4))) float f32x4;
typedef __attribute__((ext_vector_type(8))) __bf16 bf16x8;

// round-to-nearest-even f32 -> bf16 bits
static __device__ __forceinline__ unsigned int f2bf(float f) {
  unsigned int u = __float_as_uint(f);
  return (u + 0x7FFFu + ((u >> 16) & 1u)) >> 16;
}

// tanh(x) = 1 - 2/(1+e^{2x})
static __device__ __forceinline__ float fast_tanh(float x) {
  float e = __expf(2.f * x);
  return 1.f - 2.f * __builtin_amdgcn_rcpf(1.f + e);
}

// packed RNE f32x2 -> bf16x2 (single instruction)
static __device__ __forceinline__ unsigned int cvt_pk_bf16(float lo, float hi) {
  unsigned int r;
  asm("v_cvt_pk_bf16_f32 %0, %1, %2" : "=v"(r) : "v"(lo), "v"(hi));
  return r;
}

// ---------------------------------------------------------------------------
// Merged projections: pe[r][i] = enc[r][:] . W1[i][0:512]   (r < 1024)
//                     pd[r][i] = dec[r][:] . W1[i][512:1024] (r < 400)
// ---------------------------------------------------------------------------
__global__ __launch_bounds__(256) void proj_kernel(
    const float* __restrict__ enc, const float* __restrict__ dec,
    const float* __restrict__ W1, float* __restrict__ pe, float* __restrict__ pd) {
  __shared__ float As[64][17];
  __shared__ float Bs[64][17];
  const int bx = blockIdx.x;
  const float* A;
  float* P;
  int Mrows, colOff, row0;
  if (bx < 16) { A = enc; P = pe; Mrows = NB * NT; colOff = 0;  row0 = bx * 64; }
  else         { A = dec; P = pd; Mrows = NB * NU; colOff = NH; row0 = (bx - 16) * 64; }
  const int col0 = blockIdx.y * 64;
  const int tx = threadIdx.x;
  const int tr = tx >> 4, tc = tx & 15;
  const int lr = tx >> 2, lc = (tx & 3) * 4;
  float acc[4][4] = {};
  for (int k0 = 0; k0 < NH; k0 += 16) {
    float4 av = make_float4(0.f, 0.f, 0.f, 0.f);
    if (row0 + lr < Mrows)
      av = *(const float4*)(A + (size_t)(row0 + lr) * NH + k0 + lc);
    float4 bv = *(const float4*)(W1 + (size_t)(col0 + lr) * (NH + NH) + colOff + k0 + lc);
    As[lr][lc] = av.x; As[lr][lc + 1] = av.y; As[lr][lc + 2] = av.z; As[lr][lc + 3] = av.w;
    Bs[lr][lc] = bv.x; Bs[lr][lc + 1] = bv.y; Bs[lr][lc + 2] = bv.z; Bs[lr][lc + 3] = bv.w;
    __syncthreads();
#pragma unroll
    for (int kk = 0; kk < 16; ++kk) {
      float a4[4], b4[4];
#pragma unroll
      for (int i = 0; i < 4; ++i) { a4[i] = As[tr * 4 + i][kk]; b4[i] = Bs[tc * 4 + i][kk]; }
#pragma unroll
      for (int i = 0; i < 4; ++i)
#pragma unroll
        for (int j = 0; j < 4; ++j) acc[i][j] = fmaf(a4[i], b4[j], acc[i][j]);
    }
    __syncthreads();
  }
#pragma unroll
  for (int i = 0; i < 4; ++i) {
    int r = row0 + tr * 4 + i;
    if (r < Mrows) {
#pragma unroll
      for (int j = 0; j < 4; ++j)
        P[(size_t)r * NI + col0 + tc * 4 + j] = acc[i][j];
    }
  }
}

// ---------------------------------------------------------------------------
// W2 f32 -> bf16, PRE-FRAGGED for BK=32 direct-to-reg fragment loads:
// chunk g (16B) = [nt 4][kt 16][cb 16][lq 4][lr 16] ->
//   v = nt*256 + cb*16 + lr,  k = kt*32 + lq*8
// ---------------------------------------------------------------------------
__global__ __launch_bounds__(256) void cvt_w2_frag_kernel(
    const float* __restrict__ W2, unsigned short* __restrict__ w2f) {
  int g = blockIdx.x * 256 + threadIdx.x;      // 65536 chunks
  int lr = g & 15, lq = (g >> 4) & 3;
  int cb = (g >> 6) & 15, kt = (g >> 10) & 15, nt = (g >> 14) & 3;
  int v = nt * 256 + cb * 16 + lr;
  int k = kt * 32 + lq * 8;
  const float* src = W2 + (size_t)v * NI + k;
  float4 a = *(const float4*)src;
  float4 b = *(const float4*)(src + 4);
  uint4 o;
  o.x = f2bf(a.x) | (f2bf(a.y) << 16);
  o.y = f2bf(a.z) | (f2bf(a.w) << 16);
  o.z = f2bf(b.x) | (f2bf(b.y) << 16);
  o.w = f2bf(b.z) | (f2bf(b.w) << 16);
  *(uint4*)(w2f + (size_t)g * 8) = o;
}

// ---------------------------------------------------------------------------
// Fused joint GEMM, barrier-free K-loop, tanh computed exactly ONCE.
// Block: 512 thr / 8 waves (2M x 4N), 128 rows x FULL 1024 vocab.
// Phase 0: A panel tanh(pe+pd+b1) -> bf16 into 128 KB LDS (full K=512),
//          rows of 64 granules, phys slot = g ^ (row&7) (2-way reads, free).
//          ONE __syncthreads total.
// K-loop (g = 0..63: np = g>>4 vocab panel, kt = g&15, BK=32):
//   B fragments loaded DIRECT to registers from pre-fragged w2f (1 KB/wave
//   coalesced L2 hits), even/odd double-buffered (named regs, no dyn index);
//   4 x ds_read_b128 (A) + 16 MFMA per step; NO barriers, NO ds_writes ->
//   waves drift freely, MFMA/VALU/VMEM overlap across 2 waves/SIMD.
// Epilogue per vocab panel: +b2 (L1 hit), fp32 stores, re-zero acc.
// ---------------------------------------------------------------------------
__global__ __launch_bounds__(512, 2) void fused_joint_kernel(
    const float* __restrict__ pe, const float* __restrict__ pd,
    const float* __restrict__ b1, const unsigned short* __restrict__ w2f,
    const float* __restrict__ b2, float* __restrict__ out) {
  __shared__ unsigned char ldsA[131072];   // 128 rows x 512 k bf16, swizzled
  const int tx = threadIdx.x;
  const int R0 = blockIdx.x * 128;
  const int lane = tx & 63, wid = tx >> 6;
  const int wr = wid >> 2, wc = wid & 3;   // 2M x 4N; wave tile 64 x 64
  const int lr = lane & 15, lq = lane >> 4;

  // B fragment load: chunk = G*1024 + (wc*4+nf)*64 + lq*16 + lr  (16B each)
  const unsigned short* w2base = w2f + ((size_t)(wc * 4) * 64 + lq * 16 + lr) * 8;
#define LOADB(DST, G) do {                                                    \
    const unsigned short* s_ = w2base + ((size_t)(G) << 13);                  \
    DST##0 = *(const bf16x8*)(s_);                                            \
    DST##1 = *(const bf16x8*)(s_ + 512);                                      \
    DST##2 = *(const bf16x8*)(s_ + 1024);                                     \
    DST##3 = *(const bf16x8*)(s_ + 1536);                                     \
  } while (0)

  bf16x8 bA0, bA1, bA2, bA3, bB0, bB1, bB2, bB3;
  LOADB(bA, 0);                            // in flight through phase 0

  // ---- Phase 0: A panel (128 x 512) = tanh(pe+pd+b1) -> ldsA ----
#pragma unroll 2
  for (int pass = 0; pass < 16; ++pass) {
    int idx = pass * 512 + tx;             // 8192 granules of 8 elems
    int row = idx >> 6;                    // 0..127
    int g8 = idx & 63;                     // granule within row
    int i0 = g8 * 8;
    int grow = R0 + row;
    int b = grow / (NT * NU);
    int rem = grow - b * (NT * NU);
    int t = rem / NU;
    int u = rem - t * NU;
    const float* peP = pe + (size_t)(b * NT + t) * NI + i0;
    const float* pdP = pd + (size_t)(b * NU + u) * NI + i0;
    float4 p0 = *(const float4*)peP, p1 = *(const float4*)(peP + 4);
    float4 q0 = *(const float4*)pdP, q1 = *(const float4*)(pdP + 4);
    float4 c0 = *(const float4*)(b1 + i0), c1 = *(const float4*)(b1 + i0 + 4);
    uint4 pk;
    pk.x = cvt_pk_bf16(fast_tanh(p0.x + q0.x + c0.x), fast_tanh(p0.y + q0.y + c0.y));
    pk.y = cvt_pk_bf16(fast_tanh(p0.z + q0.z + c0.z), fast_tanh(p0.w + q0.w + c0.w));
    pk.z = cvt_pk_bf16(fast_tanh(p1.x + q1.x + c1.x), fast_tanh(p1.y + q1.y + c1.y));
    pk.w = cvt_pk_bf16(fast_tanh(p1.z + q1.z + c1.z), fast_tanh(p1.w + q1.w + c1.w));
    *(uint4*)(ldsA + row * 1024 + ((g8 ^ (row & 7)) << 4)) = pk;
  }
  __syncthreads();                         // the ONLY barrier

  f32x4 acc[4][4];
#pragma unroll
  for (int mf = 0; mf < 4; ++mf)
#pragma unroll
    for (int nf = 0; nf < 4; ++nf)
#pragma unroll
      for (int z = 0; z < 4; ++z) acc[mf][nf][z] = 0.f;

#define COMPUTE(BV, G) do {                                                   \
    const int kt_ = (G) & 15;                                                 \
    bf16x8 af_[4];                                                            \
    _Pragma("unroll")                                                         \
    for (int mf = 0; mf < 4; ++mf) {                                          \
      int row_ = wr * 64 + mf * 16 + lr;                                      \
      af_[mf] = *(const bf16x8*)(ldsA + row_ * 1024 +                         \
                                 (((kt_ * 4 + lq) ^ (lr & 7)) << 4));         \
    }                                                                         \
    __builtin_amdgcn_s_setprio(1);                                            \
    _Pragma("unroll")                                                         \
    for (int mf = 0; mf < 4; ++mf) {                                          \
      acc[mf][0] = __builtin_amdgcn_mfma_f32_16x16x32_bf16(af_[mf], BV##0, acc[mf][0], 0, 0, 0); \
      acc[mf][1] = __builtin_amdgcn_mfma_f32_16x16x32_bf16(af_[mf], BV##1, acc[mf][1], 0, 0, 0); \
      acc[mf][2] = __builtin_amdgcn_mfma_f32_16x16x32_bf16(af_[mf], BV##2, acc[mf][2], 0, 0, 0); \
      acc[mf][3] = __builtin_amdgcn_mfma_f32_16x16x32_bf16(af_[mf], BV##3, acc[mf][3], 0, 0, 0); \
    }                                                                         \
    __builtin_amdgcn_s_setprio(0);                                            \
    if (kt_ == 15) {                                                          \
      const int np_ = (G) >> 4;                                               \
      _Pragma("unroll")                                                       \
      for (int nf = 0; nf < 4; ++nf) {                                        \
        int col_ = np_ * 256 + wc * 64 + nf * 16 + lr;                        \
        float bb_ = b2[col_];                                                 \
        _Pragma("unroll")                                                     \
        for (int mf = 0; mf < 4; ++mf) {                                      \
          _Pragma("unroll")                                                   \
          for (int j = 0; j < 4; ++j) {                                       \
            int grow_ = R0 + wr * 64 + mf * 16 + lq * 4 + j;                  \
            out[(size_t)grow_ * NV + col_] = acc[mf][nf][j] + bb_;            \
            acc[mf][nf][j] = 0.f;                                             \
          }                                                                   \
        }                                                                     \
      }                                                                       \
    }                                                                         \
  } while (0)

  for (int g = 0; g < 64; g += 2) {
    LOADB(bB, g + 1);                      // prefetch odd step
    COMPUTE(bA, g);
    if (g + 2 < 64) LOADB(bA, g + 2);      // prefetch next even step
    COMPUTE(bB, g + 1);
  }
#undef COMPUTE
#undef LOADB
}

extern "C" void kernel_launch(void* const* d_in, const int* in_sizes, int n_in,
                              void* d_out, int out_size, void* d_ws, size_t ws_size,
                              hipStream_t stream) {
  const float* enc = (const float*)d_in[0];
  const float* dec = (const float*)d_in[1];
  const float* W1  = (const float*)d_in[2];
  const float* b1  = (const float*)d_in[3];
  const float* W2  = (const float*)d_in[4];
  const float* b2  = (const float*)d_in[5];
  float* out = (float*)d_out;
  char* ws = (char*)d_ws;

  float* pe = (float*)ws;                                   // 2 MB
  float* pd = (float*)(ws + (2u << 20));                    // 0.8 MB
  unsigned short* w2f = (unsigned short*)(ws + (3u << 20)); // 1 MB, fragged

  proj_kernel<<<dim3(23, 8), 256, 0, stream>>>(enc, dec, W1, pe, pd);
  cvt_w2_frag_kernel<<<256, 256, 0, stream>>>(W2, w2f);
  fused_joint_kernel<<<MROWS / 128, 512, 0, stream>>>(pe, pd, b1, w2f, b2, out);
}

// Round 12
// 227.517 us; speedup vs baseline: 1.6486x; 1.0049x over previous
//
#include <hip/hip_runtime.h>
#include <hip/hip_bf16.h>

// Problem constants
#define NB 4
#define NT 256
#define NU 100
#define NH 512      // H_ENC = H_DEC = 512
#define NI 512      // INNER
#define NV 1024     // VOCAB
#define MROWS (NB * NT * NU)   // 102400 joint rows

typedef __attribute__((ext_vector_type(4))) float f32x4;
typedef __attribute__((ext_vector_type(8))) __bf16 bf16x8;

// round-to-nearest-even f32 -> bf16 bits
static __device__ __forceinline__ unsigned int f2bf(float f) {
  unsigned int u = __float_as_uint(f);
  return (u + 0x7FFFu + ((u >> 16) & 1u)) >> 16;
}

// tanh(x) = 1 - 2/(1+e^{2x})
static __device__ __forceinline__ float fast_tanh(float x) {
  float e = __expf(2.f * x);
  return 1.f - 2.f * __builtin_amdgcn_rcpf(1.f + e);
}

// packed RNE f32x2 -> bf16x2 (single instruction)
static __device__ __forceinline__ unsigned int cvt_pk_bf16(float lo, float hi) {
  unsigned int r;
  asm("v_cvt_pk_bf16_f32 %0, %1, %2" : "=v"(r) : "v"(lo), "v"(hi));
  return r;
}

// ---------------------------------------------------------------------------
// Merged projections: pe[r][i] = enc[r][:] . W1[i][0:512]   (r < 1024)
//                     pd[r][i] = dec[r][:] . W1[i][512:1024] (r < 400)
// ---------------------------------------------------------------------------
__global__ __launch_bounds__(256) void proj_kernel(
    const float* __restrict__ enc, const float* __restrict__ dec,
    const float* __restrict__ W1, float* __restrict__ pe, float* __restrict__ pd) {
  __shared__ float As[64][17];
  __shared__ float Bs[64][17];
  const int bx = blockIdx.x;
  const float* A;
  float* P;
  int Mrows, colOff, row0;
  if (bx < 16) { A = enc; P = pe; Mrows = NB * NT; colOff = 0;  row0 = bx * 64; }
  else         { A = dec; P = pd; Mrows = NB * NU; colOff = NH; row0 = (bx - 16) * 64; }
  const int col0 = blockIdx.y * 64;
  const int tx = threadIdx.x;
  const int tr = tx >> 4, tc = tx & 15;
  const int lr = tx >> 2, lc = (tx & 3) * 4;
  float acc[4][4] = {};
  for (int k0 = 0; k0 < NH; k0 += 16) {
    float4 av = make_float4(0.f, 0.f, 0.f, 0.f);
    if (row0 + lr < Mrows)
      av = *(const float4*)(A + (size_t)(row0 + lr) * NH + k0 + lc);
    float4 bv = *(const float4*)(W1 + (size_t)(col0 + lr) * (NH + NH) + colOff + k0 + lc);
    As[lr][lc] = av.x; As[lr][lc + 1] = av.y; As[lr][lc + 2] = av.z; As[lr][lc + 3] = av.w;
    Bs[lr][lc] = bv.x; Bs[lr][lc + 1] = bv.y; Bs[lr][lc + 2] = bv.z; Bs[lr][lc + 3] = bv.w;
    __syncthreads();
#pragma unroll
    for (int kk = 0; kk < 16; ++kk) {
      float a4[4], b4[4];
#pragma unroll
      for (int i = 0; i < 4; ++i) { a4[i] = As[tr * 4 + i][kk]; b4[i] = Bs[tc * 4 + i][kk]; }
#pragma unroll
      for (int i = 0; i < 4; ++i)
#pragma unroll
        for (int j = 0; j < 4; ++j) acc[i][j] = fmaf(a4[i], b4[j], acc[i][j]);
    }
    __syncthreads();
  }
#pragma unroll
  for (int i = 0; i < 4; ++i) {
    int r = row0 + tr * 4 + i;
    if (r < Mrows) {
#pragma unroll
      for (int j = 0; j < 4; ++j)
        P[(size_t)r * NI + col0 + tc * 4 + j] = acc[i][j];
    }
  }
}

// ---------------------------------------------------------------------------
// W2 f32 -> bf16, PRE-FRAGGED for BK=32 direct-to-reg fragment loads:
// chunk g (16B) = [nt 4][kt 16][cb 16][lq 4][lr 16] ->
//   v = nt*256 + cb*16 + lr,  k = kt*32 + lq*8
// ---------------------------------------------------------------------------
__global__ __launch_bounds__(256) void cvt_w2_frag_kernel(
    const float* __restrict__ W2, unsigned short* __restrict__ w2f) {
  int g = blockIdx.x * 256 + threadIdx.x;      // 65536 chunks
  int lr = g & 15, lq = (g >> 4) & 3;
  int cb = (g >> 6) & 15, kt = (g >> 10) & 15, nt = (g >> 14) & 3;
  int v = nt * 256 + cb * 16 + lr;
  int k = kt * 32 + lq * 8;
  const float* src = W2 + (size_t)v * NI + k;
  float4 a = *(const float4*)src;
  float4 b = *(const float4*)(src + 4);
  uint4 o;
  o.x = f2bf(a.x) | (f2bf(a.y) << 16);
  o.y = f2bf(a.z) | (f2bf(a.w) << 16);
  o.z = f2bf(b.x) | (f2bf(b.y) << 16);
  o.w = f2bf(b.z) | (f2bf(b.w) << 16);
  *(uint4*)(w2f + (size_t)g * 8) = o;
}

// ---------------------------------------------------------------------------
// Fused joint GEMM, barrier-free K-loop, tanh exactly once, 2 blocks/CU.
// Block: 512 thr / 8 waves (2M x 4N), 64 rows x FULL 1024 vocab.
// Phase 0: A panel tanh(pe+pd+b1) -> bf16 into 64 KB LDS (full K=512),
//          rows of 64 granules, phys slot = g ^ (row&7). One barrier total.
// K-loop (g = 0..63: np = g>>4 vocab panel, kt = g&15, BK=32):
//   B fragments DIRECT to registers from pre-fragged w2f (coalesced L2/L1
//   hits; wr-duplicate addresses L1-hit), even/odd named-reg double buffer;
//   2 x ds_read_b128 (A) + 8 MFMA per step; NO barriers, NO ds_writes.
// launch_bounds(512,4): <=128 VGPR -> 16 waves/CU (4/SIMD) + 2 blocks/CU
// (LDS 64 KB) -> deep TLP; co-resident block covers phase-0/epilogue.
// Epilogue per vocab panel: +b2, fp32 stores, re-zero acc.
// ---------------------------------------------------------------------------
__global__ __launch_bounds__(512, 4) void fused_joint_kernel(
    const float* __restrict__ pe, const float* __restrict__ pd,
    const float* __restrict__ b1, const unsigned short* __restrict__ w2f,
    const float* __restrict__ b2, float* __restrict__ out) {
  __shared__ unsigned char ldsA[65536];    // 64 rows x 512 k bf16, swizzled
  const int tx = threadIdx.x;
  const int R0 = blockIdx.x * 64;
  const int lane = tx & 63, wid = tx >> 6;
  const int wr = wid >> 2, wc = wid & 3;   // 2M x 4N; wave tile 32 x 64
  const int lr = lane & 15, lq = lane >> 4;

  // B fragment load: chunk = G*1024 + (wc*4+nf)*64 + lq*16 + lr  (16B each)
  const unsigned short* w2base = w2f + ((size_t)(wc * 4) * 64 + lq * 16 + lr) * 8;
#define LOADB(DST, G) do {                                                    \
    const unsigned short* s_ = w2base + ((size_t)(G) << 13);                  \
    DST##0 = *(const bf16x8*)(s_);                                            \
    DST##1 = *(const bf16x8*)(s_ + 512);                                      \
    DST##2 = *(const bf16x8*)(s_ + 1024);                                     \
    DST##3 = *(const bf16x8*)(s_ + 1536);                                     \
  } while (0)

  bf16x8 bA0, bA1, bA2, bA3, bB0, bB1, bB2, bB3;
  LOADB(bA, 0);                            // in flight through phase 0

  // ---- Phase 0: A panel (64 x 512) = tanh(pe+pd+b1) -> ldsA ----
#pragma unroll 2
  for (int pass = 0; pass < 8; ++pass) {
    int idx = pass * 512 + tx;             // 4096 granules of 8 elems
    int row = idx >> 6;                    // 0..63
    int g8 = idx & 63;                     // granule within row
    int i0 = g8 * 8;
    int grow = R0 + row;
    int b = grow / (NT * NU);
    int rem = grow - b * (NT * NU);
    int t = rem / NU;
    int u = rem - t * NU;
    const float* peP = pe + (size_t)(b * NT + t) * NI + i0;
    const float* pdP = pd + (size_t)(b * NU + u) * NI + i0;
    float4 p0 = *(const float4*)peP, p1 = *(const float4*)(peP + 4);
    float4 q0 = *(const float4*)pdP, q1 = *(const float4*)(pdP + 4);
    float4 c0 = *(const float4*)(b1 + i0), c1 = *(const float4*)(b1 + i0 + 4);
    uint4 pk;
    pk.x = cvt_pk_bf16(fast_tanh(p0.x + q0.x + c0.x), fast_tanh(p0.y + q0.y + c0.y));
    pk.y = cvt_pk_bf16(fast_tanh(p0.z + q0.z + c0.z), fast_tanh(p0.w + q0.w + c0.w));
    pk.z = cvt_pk_bf16(fast_tanh(p1.x + q1.x + c1.x), fast_tanh(p1.y + q1.y + c1.y));
    pk.w = cvt_pk_bf16(fast_tanh(p1.z + q1.z + c1.z), fast_tanh(p1.w + q1.w + c1.w));
    *(uint4*)(ldsA + row * 1024 + ((g8 ^ (row & 7)) << 4)) = pk;
  }
  __syncthreads();                         // the ONLY barrier

  f32x4 acc[2][4];
#pragma unroll
  for (int mf = 0; mf < 2; ++mf)
#pragma unroll
    for (int nf = 0; nf < 4; ++nf)
#pragma unroll
      for (int z = 0; z < 4; ++z) acc[mf][nf][z] = 0.f;

#define COMPUTE(BV, G) do {                                                   \
    const int kt_ = (G) & 15;                                                 \
    bf16x8 af_[2];                                                            \
    _Pragma("unroll")                                                         \
    for (int mf = 0; mf < 2; ++mf) {                                          \
      int row_ = wr * 32 + mf * 16 + lr;                                      \
      af_[mf] = *(const bf16x8*)(ldsA + row_ * 1024 +                         \
                                 (((kt_ * 4 + lq) ^ (lr & 7)) << 4));         \
    }                                                                         \
    __builtin_amdgcn_s_setprio(1);                                            \
    _Pragma("unroll")                                                         \
    for (int mf = 0; mf < 2; ++mf) {                                          \
      acc[mf][0] = __builtin_amdgcn_mfma_f32_16x16x32_bf16(af_[mf], BV##0, acc[mf][0], 0, 0, 0); \
      acc[mf][1] = __builtin_amdgcn_mfma_f32_16x16x32_bf16(af_[mf], BV##1, acc[mf][1], 0, 0, 0); \
      acc[mf][2] = __builtin_amdgcn_mfma_f32_16x16x32_bf16(af_[mf], BV##2, acc[mf][2], 0, 0, 0); \
      acc[mf][3] = __builtin_amdgcn_mfma_f32_16x16x32_bf16(af_[mf], BV##3, acc[mf][3], 0, 0, 0); \
    }                                                                         \
    __builtin_amdgcn_s_setprio(0);                                            \
    if (kt_ == 15) {                                                          \
      const int np_ = (G) >> 4;                                               \
      _Pragma("unroll")                                                       \
      for (int nf = 0; nf < 4; ++nf) {                                        \
        int col_ = np_ * 256 + wc * 64 + nf * 16 + lr;                        \
        float bb_ = b2[col_];                                                 \
        _Pragma("unroll")                                                     \
        for (int mf = 0; mf < 2; ++mf) {                                      \
          _Pragma("unroll")                                                   \
          for (int j = 0; j < 4; ++j) {                                       \
            int grow_ = R0 + wr * 32 + mf * 16 + lq * 4 + j;                  \
            out[(size_t)grow_ * NV + col_] = acc[mf][nf][j] + bb_;            \
            acc[mf][nf][j] = 0.f;                                             \
          }                                                                   \
        }                                                                     \
      }                                                                       \
    }                                                                         \
  } while (0)

  for (int g = 0; g < 64; g += 2) {
    LOADB(bB, g + 1);                      // prefetch odd step
    COMPUTE(bA, g);
    if (g + 2 < 64) LOADB(bA, g + 2);      // prefetch next even step
    COMPUTE(bB, g + 1);
  }
#undef COMPUTE
#undef LOADB
}

extern "C" void kernel_launch(void* const* d_in, const int* in_sizes, int n_in,
                              void* d_out, int out_size, void* d_ws, size_t ws_size,
                              hipStream_t stream) {
  const float* enc = (const float*)d_in[0];
  const float* dec = (const float*)d_in[1];
  const float* W1  = (const float*)d_in[2];
  const float* b1  = (const float*)d_in[3];
  const float* W2  = (const float*)d_in[4];
  const float* b2  = (const float*)d_in[5];
  float* out = (float*)d_out;
  char* ws = (char*)d_ws;

  float* pe = (float*)ws;                                   // 2 MB
  float* pd = (float*)(ws + (2u << 20));                    // 0.8 MB
  unsigned short* w2f = (unsigned short*)(ws + (3u << 20)); // 1 MB, fragged

  proj_kernel<<<dim3(23, 8), 256, 0, stream>>>(enc, dec, W1, pe, pd);
  cvt_w2_frag_kernel<<<256, 256, 0, stream>>>(W2, w2f);
  fused_joint_kernel<<<MROWS / 64, 512, 0, stream>>>(pe, pd, b1, w2f, b2, out);
}